// Round 11
// baseline (157.928 us; speedup 1.0000x reference)
//
#include <hip/hip_runtime.h>
#include <math.h>

#define BB 4
#define HH 8
#define LL 2048
#define DD 64
#define SK 40            // sample_k == u == 40 for L=2048, FACTOR=5
#define BH (BB*HH)       // 32
#define NC 16            // key-chunks per (bh,u) in attn
#define CK 128           // keys per chunk (NC*CK == LL)

__device__ __forceinline__ unsigned ordu(float v) {
    unsigned u = __float_as_uint(v);
    return (u & 0x80000000u) ? ~u : (u | 0x80000000u);
}

__device__ __forceinline__ float dot4(float4 a, float4 b) {
    return a.x * b.x + a.y * b.y + a.z * b.z + a.w * b.w;
}

// ---------------------------------------------------------------------------
// Stage 1: 512 uniform blocks. Each block: M for (bhA, chunk) and (bhB=bhA+16,
// chunk) with the two bh interleaved in one depth-2 pipelined sample loop
// (same sidx — IDX is query-indexed), then one vsum task. At any instant an
// XCD hosts only 2 bh of K (4 MB = L2) -> gather served from L2, not L3.
__global__ __launch_bounds__(256) void stage1_kernel(
        const float* __restrict__ Q, const float* __restrict__ K,
        const float* __restrict__ V, const int* __restrict__ IDX,
        float* __restrict__ M, float* __restrict__ csum) {
    int tid = threadIdx.x;
    int b = blockIdx.x;               // [0,512)
    int bhLo = b & 7;                 // XCD affinity
    int bhA = bhLo + 8 * ((b >> 3) & 1);
    int bhB = bhA + 16;
    int chunk = b >> 4;               // [0,32)
    int qbase = chunk * 64;
    int w = tid >> 6, lane = tid & 63;
    int qw = lane >> 2, c = lane & 3;
    int qi = w * 16 + qw;
    int qpos = qbase + qi;

    __shared__ int sidx[64 * SK];     // 10 KB (shared across both bh)
    __shared__ float part[4][DD];

    for (int i = tid; i < 64 * SK; i += 256) sidx[i] = IDX[(size_t)qbase * SK + i];

    const float4* Q4 = (const float4*)Q;
    const float4* K4 = (const float4*)K;
    float4 qA[4], qB[4];
    #pragma unroll
    for (int j = 0; j < 4; ++j) {
        qA[j] = Q4[((size_t)bhA * LL + qpos) * 16 + j * 4 + c];
        qB[j] = Q4[((size_t)bhB * LL + qpos) * 16 + j * 4 + c];
    }
    __syncthreads();

    size_t kbA = (size_t)bhA * LL * 16;
    size_t kbB = (size_t)bhB * LL * 16;
    float mxA = -INFINITY, smA = 0.f, mxB = -INFINITY, smB = 0.f;

    // depth-2 pipeline, both bh per sample: 8 float4 in flight per lane.
    float4 a0[4], b0[4], a1[4], b1[4];
    {
        int ks = sidx[qi * SK];
        const float4* krA = K4 + kbA + (size_t)ks * 16;
        const float4* krB = K4 + kbB + (size_t)ks * 16;
        #pragma unroll
        for (int j = 0; j < 4; ++j) { a0[j] = krA[j * 4 + c]; b0[j] = krB[j * 4 + c]; }
    }
    for (int s = 0; s < SK; s += 2) {
        {   // issue sample s+1 (SK even -> valid)
            int ks = sidx[qi * SK + s + 1];
            const float4* krA = K4 + kbA + (size_t)ks * 16;
            const float4* krB = K4 + kbB + (size_t)ks * 16;
            #pragma unroll
            for (int j = 0; j < 4; ++j) { a1[j] = krA[j * 4 + c]; b1[j] = krB[j * 4 + c]; }
        }
        {   // consume sample s
            float pA = dot4(qA[0], a0[0]) + dot4(qA[1], a0[1])
                     + dot4(qA[2], a0[2]) + dot4(qA[3], a0[3]);
            float pB = dot4(qB[0], b0[0]) + dot4(qB[1], b0[1])
                     + dot4(qB[2], b0[2]) + dot4(qB[3], b0[3]);
            pA += __shfl_xor(pA, 1, 64); pA += __shfl_xor(pA, 2, 64);
            pB += __shfl_xor(pB, 1, 64); pB += __shfl_xor(pB, 2, 64);
            mxA = fmaxf(mxA, pA); smA += pA;
            mxB = fmaxf(mxB, pB); smB += pB;
        }
        if (s + 2 < SK) {   // issue sample s+2
            int ks = sidx[qi * SK + s + 2];
            const float4* krA = K4 + kbA + (size_t)ks * 16;
            const float4* krB = K4 + kbB + (size_t)ks * 16;
            #pragma unroll
            for (int j = 0; j < 4; ++j) { a0[j] = krA[j * 4 + c]; b0[j] = krB[j * 4 + c]; }
        }
        {   // consume sample s+1
            float pA = dot4(qA[0], a1[0]) + dot4(qA[1], a1[1])
                     + dot4(qA[2], a1[2]) + dot4(qA[3], a1[3]);
            float pB = dot4(qB[0], b1[0]) + dot4(qB[1], b1[1])
                     + dot4(qB[2], b1[2]) + dot4(qB[3], b1[3]);
            pA += __shfl_xor(pA, 1, 64); pA += __shfl_xor(pA, 2, 64);
            pB += __shfl_xor(pB, 1, 64); pB += __shfl_xor(pB, 2, 64);
            mxA = fmaxf(mxA, pA); smA += pA;
            mxB = fmaxf(mxB, pB); smB += pB;
        }
    }
    if (c == 0) {
        M[(size_t)bhA * LL + qpos] = mxA - smA * (1.0f / (float)LL);
        M[(size_t)bhB * LL + qpos] = mxB - smB * (1.0f / (float)LL);
    }

    // ----- vsum task (deferred so V streaming doesn't evict K during M phase)
    {
        int bhv = (b & 7) + 8 * ((b >> 3) & 3);   // bijective over (bhv, cv)
        int cv = b >> 5;                          // [0,16)
        int d = tid & 63, sg = tid >> 6;
        size_t base = (size_t)bhv * LL * DD;
        int row0 = cv * 128 + sg * 32;
        float s2 = 0.f;
        for (int j = 0; j < 32; ++j) s2 += V[base + (size_t)(row0 + j) * DD + d];
        part[sg][d] = s2;
        __syncthreads();
        if (sg == 0)
            csum[((size_t)bhv * 16 + cv) * DD + d] =
                part[0][d] + part[1][d] + part[2][d] + part[3][d];
    }
}

// ---------------------------------------------------------------------------
// Fused attn (with inline per-block radix top-40) + cumsum.
// Blocks [0,512): attn chunks; blocks [512,1024): V cumsum -> out.
__global__ __launch_bounds__(256) void attn_cumsum_kernel(
        const float* __restrict__ Q, const float* __restrict__ K,
        const float* __restrict__ V, const float* __restrict__ M,
        const float* __restrict__ csum, float* __restrict__ out,
        float* __restrict__ pm, float* __restrict__ pl,
        float* __restrict__ po, int* __restrict__ topk) {
    int tid = threadIdx.x;
    __shared__ int qp[SK];
    __shared__ float4 sq4[SK][16];     // 10 KB
    __shared__ float SC[CK][SK + 1];   // 21 KB
    __shared__ float part[4][DD];      // 1 KB (cumsum)
    __shared__ unsigned hist[256], sfx[256];
    __shared__ int eqlist[128], qtmp[SK];
    __shared__ unsigned bc_prefix, bc_need, cnt_gt, cnt_eq;

    if (blockIdx.x < 512) {
        // ================= attn chunk =================
        int x = blockIdx.x;
        int bhLo = x & 7;                 // XCD affinity
        int r = x >> 3;                   // [0,64)
        int c = r & 15;                   // chunk [0,NC)
        int bhHi = r >> 4;                // [0,4)
        int bh = bhHi * 8 + bhLo;
        int w = tid >> 6, lane = tid & 63;
        int cbase = c * CK;

        // ---- inline radix top-40 of M[bh] (deterministic set; sorted below)
        unsigned v[8];
        #pragma unroll
        for (int j = 0; j < 8; ++j)
            v[j] = ordu(M[(size_t)bh * LL + tid + j * 256]);

        unsigned prefix = 0, need = SK;
        #pragma unroll
        for (int pass = 0; pass < 4; ++pass) {
            const int s = 24 - 8 * pass;
            const unsigned maskHigh = (pass == 0) ? 0u : (0xFFFFFFFFu << (s + 8));
            hist[tid] = 0;
            __syncthreads();
            #pragma unroll
            for (int j = 0; j < 8; ++j)
                if (((v[j] ^ prefix) & maskHigh) == 0)
                    atomicAdd(&hist[(v[j] >> s) & 0xFF], 1u);
            __syncthreads();
            sfx[tid] = hist[tid];
            __syncthreads();
            #pragma unroll
            for (int off = 1; off < 256; off <<= 1) {
                unsigned t = (tid + off < 256) ? sfx[tid + off] : 0u;
                __syncthreads();
                sfx[tid] += t;
                __syncthreads();
            }
            unsigned above = (tid < 255) ? sfx[tid + 1] : 0u;
            if (above < need && sfx[tid] >= need) {
                bc_prefix = prefix | ((unsigned)tid << s);
                bc_need = need - above;
            }
            __syncthreads();
            prefix = bc_prefix;
            need = bc_need;
            __syncthreads();
        }
        unsigned T = prefix;
        if (tid == 0) { cnt_gt = 0; cnt_eq = 0; }
        __syncthreads();
        #pragma unroll
        for (int j = 0; j < 8; ++j) {
            int idx = tid + j * 256;
            if (v[j] > T) { unsigned p = atomicAdd(&cnt_gt, 1u); qtmp[p] = idx; }
            else if (v[j] == T) { unsigned p = atomicAdd(&cnt_eq, 1u); if (p < 128) eqlist[p] = idx; }
        }
        __syncthreads();
        if (tid == 0) {
            int ne = (int)min(cnt_eq, 128u);
            unsigned base = cnt_gt;       // == SK - need
            for (unsigned r2 = 0; r2 < need; ++r2) {
                int bj = 0, bv = 0x7FFFFFFF;
                for (int j = 0; j < ne; ++j)
                    if (eqlist[j] < bv) { bv = eqlist[j]; bj = j; }
                qtmp[base + r2] = bv;
                eqlist[bj] = 0x7FFFFFFF;
            }
        }
        __syncthreads();
        // rank-sort ascending -> identical u-ordering across all chunks of bh
        if (tid < SK) {
            int mine = qtmp[tid];
            int rank = 0;
            for (int j = 0; j < SK; ++j) rank += (qtmp[j] < mine);
            qp[rank] = mine;
        }
        __syncthreads();
        if (c == 0 && tid < SK) topk[bh * SK + tid] = qp[tid];   // for combine

        const float4* Q4 = (const float4*)Q;
        const float4* K4 = (const float4*)K;
        const float4* V4 = (const float4*)V;
        for (int i = tid; i < SK * 16; i += 256) {
            int u = i >> 4, j = i & 15;
            sq4[u][j] = Q4[((size_t)bh * LL + qp[u]) * 16 + j];
        }
        __syncthreads();

        // ---- Phase A: scores. thread = (key kk, half of D).
        {
            int half = tid & 1;
            int kk = tid >> 1;            // [0,128)
            int kg = cbase + kk;
            size_t kb4 = (size_t)bh * LL * 16;
            float4 kreg[8];
            const float4* kr = K4 + kb4 + (size_t)kg * 16 + half * 8;
            #pragma unroll
            for (int j = 0; j < 8; ++j) kreg[j] = kr[j];
            #pragma unroll 4
            for (int u = 0; u < SK; ++u) {
                int qpu = qp[u];
                if (cbase > qpu) {
                    if (half == 0) SC[kk][u] = -INFINITY;
                    continue;
                }
                float pa = 0.f, pb = 0.f;
                #pragma unroll
                for (int j = 0; j < 4; ++j) {
                    float4 qv = sq4[u][half * 8 + j];
                    pa += kreg[j].x * qv.x + kreg[j].y * qv.y + kreg[j].z * qv.z + kreg[j].w * qv.w;
                }
                #pragma unroll
                for (int j = 4; j < 8; ++j) {
                    float4 qv = sq4[u][half * 8 + j];
                    pb += kreg[j].x * qv.x + kreg[j].y * qv.y + kreg[j].z * qv.z + kreg[j].w * qv.w;
                }
                float p = pa + pb;
                p += __shfl_xor(p, 1, 64);
                if (half == 0) SC[kk][u] = (kg <= qpu) ? p * 0.125f : -INFINITY;
            }
        }
        __syncthreads();

        // ---- Phase B: per-u chunk max + exp + sumexp
        for (int u = w; u < SK; u += 4) {
            float s0 = SC[lane][u], s1 = SC[lane + 64][u];
            float m = fmaxf(s0, s1);
            #pragma unroll
            for (int off = 32; off > 0; off >>= 1) m = fmaxf(m, __shfl_xor(m, off, 64));
            float e0 = 0.f, e1 = 0.f;
            if (m != -INFINITY) {
                e0 = expf(s0 - m);
                e1 = expf(s1 - m);
            }
            SC[lane][u] = e0;
            SC[lane + 64][u] = e1;
            float ls = e0 + e1;
            #pragma unroll
            for (int off = 32; off > 0; off >>= 1) ls += __shfl_xor(ls, off, 64);
            if (lane == 0) {
                size_t pb = (size_t)(bh * SK + u) * NC + c;
                pm[pb] = m;
                pl[pb] = ls;
            }
        }
        __syncthreads();

        // ---- Phase C: PV
        {
            int ks = tid & 3;
            int dg = (tid >> 2) & 15;
            int ug = tid >> 6;
            int u0 = ug * 10;
            float4 acc[10];
            #pragma unroll
            for (int i = 0; i < 10; ++i) acc[i] = make_float4(0.f, 0.f, 0.f, 0.f);
            for (int t = 0; t < CK / 4; ++t) {
                int k = t * 4 + ks;
                float4 vv = V4[((size_t)bh * LL + cbase + k) * 16 + dg];
                #pragma unroll
                for (int i = 0; i < 10; ++i) {
                    float pw = SC[k][u0 + i];
                    acc[i].x += pw * vv.x; acc[i].y += pw * vv.y;
                    acc[i].z += pw * vv.z; acc[i].w += pw * vv.w;
                }
            }
            #pragma unroll
            for (int i = 0; i < 10; ++i) {
                acc[i].x += __shfl_xor(acc[i].x, 1, 64); acc[i].x += __shfl_xor(acc[i].x, 2, 64);
                acc[i].y += __shfl_xor(acc[i].y, 1, 64); acc[i].y += __shfl_xor(acc[i].y, 2, 64);
                acc[i].z += __shfl_xor(acc[i].z, 1, 64); acc[i].z += __shfl_xor(acc[i].z, 2, 64);
                acc[i].w += __shfl_xor(acc[i].w, 1, 64); acc[i].w += __shfl_xor(acc[i].w, 2, 64);
            }
            if (ks == 0) {
                #pragma unroll
                for (int i = 0; i < 10; ++i) {
                    float4* dst = (float4*)&po[((size_t)(bh * SK + u0 + i) * NC + c) * DD + dg * 4];
                    *dst = acc[i];
                }
            }
        }
    } else {
        // ================= cumsum chunk =================
        int x = blockIdx.x - 512;
        int bhLo = x & 7, r = x >> 3;
        int bhHi = r & 3, c = r >> 2;
        int bh = bhHi * 8 + bhLo;
        int d = tid & 63, sg = tid >> 6;
        size_t base = (size_t)bh * LL * DD;
        int row0 = c * 128 + sg * 32;
        float v[32];
        #pragma unroll
        for (int j = 0; j < 32; ++j) v[j] = V[base + (size_t)(row0 + j) * DD + d];
        float s = 0.f;
        #pragma unroll
        for (int j = 0; j < 32; ++j) s += v[j];
        part[sg][d] = s;
        __syncthreads();
        float pre = 0.f;
        for (int cc = 0; cc < c; ++cc) pre += csum[((size_t)bh * 16 + cc) * DD + d];
        for (int ss = 0; ss < sg; ++ss) pre += part[ss][d];
        float acc = pre;
        #pragma unroll
        for (int j = 0; j < 32; ++j) {
            acc += v[j];
            out[base + (size_t)(row0 + j) * DD + d] = acc;
        }
    }
}

// ---------------------------------------------------------------------------
// combine: merge NC partials per (bh,u). One wave per group; 4 groups/block.
__global__ __launch_bounds__(256) void combine_kernel(
        const float* __restrict__ pm, const float* __restrict__ pl,
        const float* __restrict__ po, const int* __restrict__ topk,
        float* __restrict__ out) {
    int g = blockIdx.x * 4 + (threadIdx.x >> 6);   // [0, 1280)
    int d = threadIdx.x & 63;
    int qpos = topk[g];
    int bh = g / SK;
    size_t gb = (size_t)g * NC;
    float gm = -INFINITY;
    #pragma unroll
    for (int j = 0; j < NC; ++j) gm = fmaxf(gm, pm[gb + j]);
    float L = 0.f, o = 0.f;
    #pragma unroll
    for (int j = 0; j < NC; ++j) {
        float pmj = pm[gb + j];
        float wj = (pmj == -INFINITY) ? 0.f : expf(pmj - gm);
        L += pl[gb + j] * wj;
        o += po[(gb + j) * DD + d] * wj;
    }
    out[((size_t)bh * LL + qpos) * DD + d] = o / L;
}

// ---------------------------------------------------------------------------
extern "C" void kernel_launch(void* const* d_in, const int* in_sizes, int n_in,
                              void* d_out, int out_size, void* d_ws, size_t ws_size,
                              hipStream_t stream) {
    const float* Q   = (const float*)d_in[0];
    const float* K   = (const float*)d_in[1];
    const float* V   = (const float*)d_in[2];
    const int*   IDX = (const int*)d_in[3];
    float* out = (float*)d_out;

    char* ws = (char*)d_ws;
    float* M    = (float*)ws;  ws += (size_t)BH * LL * sizeof(float);                 // 256 KB
    int*   topk = (int*)ws;    ws += ((size_t)BH * SK * sizeof(int) + 255) & ~255ull;
    float* csum = (float*)ws;  ws += (size_t)BH * 16 * DD * sizeof(float);            // 128 KB
    float* pm   = (float*)ws;  ws += ((size_t)BH * SK * NC * sizeof(float) + 255) & ~255ull;
    float* pl   = (float*)ws;  ws += ((size_t)BH * SK * NC * sizeof(float) + 255) & ~255ull;
    float* po   = (float*)ws;  // BH*SK*NC*DD floats = 5.24 MB

    stage1_kernel<<<512, 256, 0, stream>>>(Q, K, V, IDX, M, csum);
    attn_cumsum_kernel<<<1024, 256, 0, stream>>>(Q, K, V, M, csum, out, pm, pl, po, topk);
    combine_kernel<<<320, 256, 0, stream>>>(pm, pl, po, topk, out);
}

// Round 12
// 154.112 us; speedup vs baseline: 1.0248x; 1.0248x over previous
//
#include <hip/hip_runtime.h>
#include <math.h>

#define BB 4
#define HH 8
#define LL 2048
#define DD 64
#define SK 40            // sample_k == u == 40 for L=2048, FACTOR=5
#define BH (BB*HH)       // 32
#define NC 16            // key-chunks per (bh,u) in attn
#define CK 128           // keys per chunk (NC*CK == LL)

__device__ __forceinline__ unsigned ordu(float v) {
    unsigned u = __float_as_uint(v);
    return (u & 0x80000000u) ? ~u : (u | 0x80000000u);
}

__device__ __forceinline__ float dot4(float4 a, float4 b) {
    return a.x * b.x + a.y * b.y + a.z * b.z + a.w * b.w;
}

// ---------------------------------------------------------------------------
// Stage 1: 512 uniform blocks. Each block: M for (bhA, chunk) and (bhB=bhA+16,
// chunk) with the two bh interleaved in one depth-2 pipelined sample loop
// (same sidx — IDX is query-indexed), then one vsum task. At any instant an
// XCD hosts only 2 bh of K (4 MB = L2) -> gather served from L2, not L3.
__global__ __launch_bounds__(256) void stage1_kernel(
        const float* __restrict__ Q, const float* __restrict__ K,
        const float* __restrict__ V, const int* __restrict__ IDX,
        float* __restrict__ M, float* __restrict__ csum) {
    int tid = threadIdx.x;
    int b = blockIdx.x;               // [0,512)
    int bhLo = b & 7;                 // XCD affinity
    int bhA = bhLo + 8 * ((b >> 3) & 1);
    int bhB = bhA + 16;
    int chunk = b >> 4;               // [0,32)
    int qbase = chunk * 64;
    int w = tid >> 6, lane = tid & 63;
    int qw = lane >> 2, c = lane & 3;
    int qi = w * 16 + qw;
    int qpos = qbase + qi;

    __shared__ int sidx[64 * SK];     // 10 KB (shared across both bh)
    __shared__ float part[4][DD];

    for (int i = tid; i < 64 * SK; i += 256) sidx[i] = IDX[(size_t)qbase * SK + i];

    const float4* Q4 = (const float4*)Q;
    const float4* K4 = (const float4*)K;
    float4 qA[4], qB[4];
    #pragma unroll
    for (int j = 0; j < 4; ++j) {
        qA[j] = Q4[((size_t)bhA * LL + qpos) * 16 + j * 4 + c];
        qB[j] = Q4[((size_t)bhB * LL + qpos) * 16 + j * 4 + c];
    }
    __syncthreads();

    size_t kbA = (size_t)bhA * LL * 16;
    size_t kbB = (size_t)bhB * LL * 16;
    float mxA = -INFINITY, smA = 0.f, mxB = -INFINITY, smB = 0.f;

    // depth-2 pipeline, both bh per sample: 8 float4 in flight per lane.
    float4 a0[4], b0[4], a1[4], b1[4];
    {
        int ks = sidx[qi * SK];
        const float4* krA = K4 + kbA + (size_t)ks * 16;
        const float4* krB = K4 + kbB + (size_t)ks * 16;
        #pragma unroll
        for (int j = 0; j < 4; ++j) { a0[j] = krA[j * 4 + c]; b0[j] = krB[j * 4 + c]; }
    }
    for (int s = 0; s < SK; s += 2) {
        {   // issue sample s+1 (SK even -> valid)
            int ks = sidx[qi * SK + s + 1];
            const float4* krA = K4 + kbA + (size_t)ks * 16;
            const float4* krB = K4 + kbB + (size_t)ks * 16;
            #pragma unroll
            for (int j = 0; j < 4; ++j) { a1[j] = krA[j * 4 + c]; b1[j] = krB[j * 4 + c]; }
        }
        {   // consume sample s
            float pA = dot4(qA[0], a0[0]) + dot4(qA[1], a0[1])
                     + dot4(qA[2], a0[2]) + dot4(qA[3], a0[3]);
            float pB = dot4(qB[0], b0[0]) + dot4(qB[1], b0[1])
                     + dot4(qB[2], b0[2]) + dot4(qB[3], b0[3]);
            pA += __shfl_xor(pA, 1, 64); pA += __shfl_xor(pA, 2, 64);
            pB += __shfl_xor(pB, 1, 64); pB += __shfl_xor(pB, 2, 64);
            mxA = fmaxf(mxA, pA); smA += pA;
            mxB = fmaxf(mxB, pB); smB += pB;
        }
        if (s + 2 < SK) {   // issue sample s+2
            int ks = sidx[qi * SK + s + 2];
            const float4* krA = K4 + kbA + (size_t)ks * 16;
            const float4* krB = K4 + kbB + (size_t)ks * 16;
            #pragma unroll
            for (int j = 0; j < 4; ++j) { a0[j] = krA[j * 4 + c]; b0[j] = krB[j * 4 + c]; }
        }
        {   // consume sample s+1
            float pA = dot4(qA[0], a1[0]) + dot4(qA[1], a1[1])
                     + dot4(qA[2], a1[2]) + dot4(qA[3], a1[3]);
            float pB = dot4(qB[0], b1[0]) + dot4(qB[1], b1[1])
                     + dot4(qB[2], b1[2]) + dot4(qB[3], b1[3]);
            pA += __shfl_xor(pA, 1, 64); pA += __shfl_xor(pA, 2, 64);
            pB += __shfl_xor(pB, 1, 64); pB += __shfl_xor(pB, 2, 64);
            mxA = fmaxf(mxA, pA); smA += pA;
            mxB = fmaxf(mxB, pB); smB += pB;
        }
    }
    if (c == 0) {
        M[(size_t)bhA * LL + qpos] = mxA - smA * (1.0f / (float)LL);
        M[(size_t)bhB * LL + qpos] = mxB - smB * (1.0f / (float)LL);
    }

    // ----- vsum task (deferred so V streaming doesn't evict K during M phase)
    {
        int bhv = (b & 7) + 8 * ((b >> 3) & 3);   // bijective over (bhv, cv)
        int cv = b >> 5;                          // [0,16)
        int d = tid & 63, sg = tid >> 6;
        size_t base = (size_t)bhv * LL * DD;
        int row0 = cv * 128 + sg * 32;
        float s2 = 0.f;
        for (int j = 0; j < 32; ++j) s2 += V[base + (size_t)(row0 + j) * DD + d];
        part[sg][d] = s2;
        __syncthreads();
        if (sg == 0)
            csum[((size_t)bhv * 16 + cv) * DD + d] =
                part[0][d] + part[1][d] + part[2][d] + part[3][d];
    }
}

// ---------------------------------------------------------------------------
// radix top-40 of M (8 bits/pass, 4 passes); parallel suffix scan. 32 blocks.
__global__ __launch_bounds__(256) void radix_kernel(
        const float* __restrict__ M, int* __restrict__ topk) {
    int tid = threadIdx.x;
    int bh = blockIdx.x;
    __shared__ unsigned hist[256];
    __shared__ unsigned sfx[256];
    __shared__ unsigned bc_prefix, bc_need;
    __shared__ unsigned cnt_gt, cnt_eq;
    __shared__ int eqlist[128];

    unsigned v[8];
    #pragma unroll
    for (int j = 0; j < 8; ++j)
        v[j] = ordu(M[(size_t)bh * LL + tid + j * 256]);

    unsigned prefix = 0, need = SK;
    #pragma unroll
    for (int pass = 0; pass < 4; ++pass) {
        const int s = 24 - 8 * pass;
        const unsigned maskHigh = (pass == 0) ? 0u : (0xFFFFFFFFu << (s + 8));
        hist[tid] = 0;
        __syncthreads();
        #pragma unroll
        for (int j = 0; j < 8; ++j)
            if (((v[j] ^ prefix) & maskHigh) == 0)
                atomicAdd(&hist[(v[j] >> s) & 0xFF], 1u);
        __syncthreads();
        sfx[tid] = hist[tid];
        __syncthreads();
        #pragma unroll
        for (int off = 1; off < 256; off <<= 1) {
            unsigned t = (tid + off < 256) ? sfx[tid + off] : 0u;
            __syncthreads();
            sfx[tid] += t;
            __syncthreads();
        }
        unsigned above = (tid < 255) ? sfx[tid + 1] : 0u;
        if (above < need && sfx[tid] >= need) {
            bc_prefix = prefix | ((unsigned)tid << s);
            bc_need = need - above;
        }
        __syncthreads();
        prefix = bc_prefix;
        need = bc_need;
        __syncthreads();
    }
    unsigned T = prefix;
    if (tid == 0) { cnt_gt = 0; cnt_eq = 0; }
    __syncthreads();
    #pragma unroll
    for (int j = 0; j < 8; ++j) {
        int idx = tid + j * 256;
        if (v[j] > T) { unsigned p = atomicAdd(&cnt_gt, 1u); topk[bh * SK + p] = idx; }
        else if (v[j] == T) { unsigned p = atomicAdd(&cnt_eq, 1u); if (p < 128) eqlist[p] = idx; }
    }
    __syncthreads();
    if (tid == 0) {
        int ne = (int)min(cnt_eq, 128u);
        unsigned base = cnt_gt;       // == SK - need
        for (unsigned r2 = 0; r2 < need; ++r2) {
            int bj = 0, bv = 0x7FFFFFFF;
            for (int j = 0; j < ne; ++j)
                if (eqlist[j] < bv) { bv = eqlist[j]; bj = j; }
            topk[bh * SK + base + r2] = bv;
            eqlist[bj] = 0x7FFFFFFF;
        }
    }
}

// ---------------------------------------------------------------------------
// Fused attn + cumsum (round-10 version: external topk, no inline radix).
// Blocks [0,512): attn chunks; blocks [512,1024): V cumsum -> out.
__global__ __launch_bounds__(256) void attn_cumsum_kernel(
        const float* __restrict__ Q, const float* __restrict__ K,
        const float* __restrict__ V, const int* __restrict__ topk,
        const float* __restrict__ csum, float* __restrict__ out,
        float* __restrict__ pm, float* __restrict__ pl,
        float* __restrict__ po) {
    int tid = threadIdx.x;
    __shared__ int qp[SK];
    __shared__ float4 sq4[SK][16];     // 10 KB
    __shared__ float SC[CK][SK + 1];   // 21 KB
    __shared__ float part[4][DD];      // 1 KB (cumsum)

    if (blockIdx.x < 512) {
        // ================= attn chunk =================
        int x = blockIdx.x;
        int bhLo = x & 7;                 // XCD affinity
        int r = x >> 3;                   // [0,64)
        int c = r & 15;                   // chunk [0,NC)
        int bhHi = r >> 4;                // [0,4)
        int bh = bhHi * 8 + bhLo;
        int w = tid >> 6, lane = tid & 63;
        int cbase = c * CK;

        if (tid < SK) qp[tid] = topk[bh * SK + tid];
        __syncthreads();
        const float4* Q4 = (const float4*)Q;
        const float4* K4 = (const float4*)K;
        const float4* V4 = (const float4*)V;
        for (int i = tid; i < SK * 16; i += 256) {
            int u = i >> 4, j = i & 15;
            sq4[u][j] = Q4[((size_t)bh * LL + qp[u]) * 16 + j];
        }
        __syncthreads();

        // ---- Phase A: scores. thread = (key kk, half of D).
        {
            int half = tid & 1;
            int kk = tid >> 1;            // [0,128)
            int kg = cbase + kk;
            size_t kb4 = (size_t)bh * LL * 16;
            float4 kreg[8];
            const float4* kr = K4 + kb4 + (size_t)kg * 16 + half * 8;
            #pragma unroll
            for (int j = 0; j < 8; ++j) kreg[j] = kr[j];
            #pragma unroll 4
            for (int u = 0; u < SK; ++u) {
                int qpu = qp[u];
                if (cbase > qpu) {
                    if (half == 0) SC[kk][u] = -INFINITY;
                    continue;
                }
                float pa = 0.f, pb = 0.f;
                #pragma unroll
                for (int j = 0; j < 4; ++j) {
                    float4 qv = sq4[u][half * 8 + j];
                    pa += kreg[j].x * qv.x + kreg[j].y * qv.y + kreg[j].z * qv.z + kreg[j].w * qv.w;
                }
                #pragma unroll
                for (int j = 4; j < 8; ++j) {
                    float4 qv = sq4[u][half * 8 + j];
                    pb += kreg[j].x * qv.x + kreg[j].y * qv.y + kreg[j].z * qv.z + kreg[j].w * qv.w;
                }
                float p = pa + pb;
                p += __shfl_xor(p, 1, 64);
                if (half == 0) SC[kk][u] = (kg <= qpu) ? p * 0.125f : -INFINITY;
            }
        }
        __syncthreads();

        // ---- Phase B: per-u chunk max + exp + sumexp
        for (int u = w; u < SK; u += 4) {
            float s0 = SC[lane][u], s1 = SC[lane + 64][u];
            float m = fmaxf(s0, s1);
            #pragma unroll
            for (int off = 32; off > 0; off >>= 1) m = fmaxf(m, __shfl_xor(m, off, 64));
            float e0 = 0.f, e1 = 0.f;
            if (m != -INFINITY) {
                e0 = expf(s0 - m);
                e1 = expf(s1 - m);
            }
            SC[lane][u] = e0;
            SC[lane + 64][u] = e1;
            float ls = e0 + e1;
            #pragma unroll
            for (int off = 32; off > 0; off >>= 1) ls += __shfl_xor(ls, off, 64);
            if (lane == 0) {
                size_t pb = (size_t)(bh * SK + u) * NC + c;
                pm[pb] = m;
                pl[pb] = ls;
            }
        }
        __syncthreads();

        // ---- Phase C: PV
        {
            int ks = tid & 3;
            int dg = (tid >> 2) & 15;
            int ug = tid >> 6;
            int u0 = ug * 10;
            float4 acc[10];
            #pragma unroll
            for (int i = 0; i < 10; ++i) acc[i] = make_float4(0.f, 0.f, 0.f, 0.f);
            for (int t = 0; t < CK / 4; ++t) {
                int k = t * 4 + ks;
                float4 vv = V4[((size_t)bh * LL + cbase + k) * 16 + dg];
                #pragma unroll
                for (int i = 0; i < 10; ++i) {
                    float pw = SC[k][u0 + i];
                    acc[i].x += pw * vv.x; acc[i].y += pw * vv.y;
                    acc[i].z += pw * vv.z; acc[i].w += pw * vv.w;
                }
            }
            #pragma unroll
            for (int i = 0; i < 10; ++i) {
                acc[i].x += __shfl_xor(acc[i].x, 1, 64); acc[i].x += __shfl_xor(acc[i].x, 2, 64);
                acc[i].y += __shfl_xor(acc[i].y, 1, 64); acc[i].y += __shfl_xor(acc[i].y, 2, 64);
                acc[i].z += __shfl_xor(acc[i].z, 1, 64); acc[i].z += __shfl_xor(acc[i].z, 2, 64);
                acc[i].w += __shfl_xor(acc[i].w, 1, 64); acc[i].w += __shfl_xor(acc[i].w, 2, 64);
            }
            if (ks == 0) {
                #pragma unroll
                for (int i = 0; i < 10; ++i) {
                    float4* dst = (float4*)&po[((size_t)(bh * SK + u0 + i) * NC + c) * DD + dg * 4];
                    *dst = acc[i];
                }
            }
        }
    } else {
        // ================= cumsum chunk =================
        int x = blockIdx.x - 512;
        int bhLo = x & 7, r = x >> 3;
        int bhHi = r & 3, c = r >> 2;
        int bh = bhHi * 8 + bhLo;
        int d = tid & 63, sg = tid >> 6;
        size_t base = (size_t)bh * LL * DD;
        int row0 = c * 128 + sg * 32;
        float v[32];
        #pragma unroll
        for (int j = 0; j < 32; ++j) v[j] = V[base + (size_t)(row0 + j) * DD + d];
        float s = 0.f;
        #pragma unroll
        for (int j = 0; j < 32; ++j) s += v[j];
        part[sg][d] = s;
        __syncthreads();
        float pre = 0.f;
        for (int cc = 0; cc < c; ++cc) pre += csum[((size_t)bh * 16 + cc) * DD + d];
        for (int ss = 0; ss < sg; ++ss) pre += part[ss][d];
        float acc = pre;
        #pragma unroll
        for (int j = 0; j < 32; ++j) {
            acc += v[j];
            out[base + (size_t)(row0 + j) * DD + d] = acc;
        }
    }
}

// ---------------------------------------------------------------------------
// combine: merge NC partials per (bh,u). One wave per group; 4 groups/block.
__global__ __launch_bounds__(256) void combine_kernel(
        const float* __restrict__ pm, const float* __restrict__ pl,
        const float* __restrict__ po, const int* __restrict__ topk,
        float* __restrict__ out) {
    int g = blockIdx.x * 4 + (threadIdx.x >> 6);   // [0, 1280)
    int d = threadIdx.x & 63;
    int qpos = topk[g];
    int bh = g / SK;
    size_t gb = (size_t)g * NC;
    float gm = -INFINITY;
    #pragma unroll
    for (int j = 0; j < NC; ++j) gm = fmaxf(gm, pm[gb + j]);
    float L = 0.f, o = 0.f;
    #pragma unroll
    for (int j = 0; j < NC; ++j) {
        float pmj = pm[gb + j];
        float wj = (pmj == -INFINITY) ? 0.f : expf(pmj - gm);
        L += pl[gb + j] * wj;
        o += po[(gb + j) * DD + d] * wj;
    }
    out[((size_t)bh * LL + qpos) * DD + d] = o / L;
}

// ---------------------------------------------------------------------------
extern "C" void kernel_launch(void* const* d_in, const int* in_sizes, int n_in,
                              void* d_out, int out_size, void* d_ws, size_t ws_size,
                              hipStream_t stream) {
    const float* Q   = (const float*)d_in[0];
    const float* K   = (const float*)d_in[1];
    const float* V   = (const float*)d_in[2];
    const int*   IDX = (const int*)d_in[3];
    float* out = (float*)d_out;

    char* ws = (char*)d_ws;
    float* M    = (float*)ws;  ws += (size_t)BH * LL * sizeof(float);                 // 256 KB
    int*   topk = (int*)ws;    ws += ((size_t)BH * SK * sizeof(int) + 255) & ~255ull;
    float* csum = (float*)ws;  ws += (size_t)BH * 16 * DD * sizeof(float);            // 128 KB
    float* pm   = (float*)ws;  ws += ((size_t)BH * SK * NC * sizeof(float) + 255) & ~255ull;
    float* pl   = (float*)ws;  ws += ((size_t)BH * SK * NC * sizeof(float) + 255) & ~255ull;
    float* po   = (float*)ws;  // BH*SK*NC*DD floats = 5.24 MB

    stage1_kernel<<<512, 256, 0, stream>>>(Q, K, V, IDX, M, csum);
    radix_kernel<<<32, 256, 0, stream>>>(M, topk);
    attn_cumsum_kernel<<<1024, 256, 0, stream>>>(Q, K, V, topk, csum, out, pm, pl, po);
    combine_kernel<<<320, 256, 0, stream>>>(pm, pl, po, topk, out);
}